// Round 2
// baseline (1135.640 us; speedup 1.0000x reference)
//
#include <hip/hip_runtime.h>

// StateTrajectoryNetwork: s' = s + 2 * W4·tanh(W3·tanh(W2·tanh(W1·[x;s]) + b2))
// S=4096 sequential steps, B=16384 independent chains -> 1 thread per chain.
//
// tanh folding: tanh(y) = 1 - 2*z, z = 1/(1 + exp2(K*y)), K = 2/ln(2).
// Next-layer weights absorb the affine (1 - 2z):
//   arg_i = K*(b_i + sum_j W_ij) + sum_j (-2K*W_ij) * z_j
// so each layer is: 4 fma-dots -> exp2 -> +1 -> rcp. Exact math identical to
// reference; only fp32 rounding differs (~few ulp/step).

#define EXP2F(a) __builtin_amdgcn_exp2f(a)
#define RCPF(a)  __builtin_amdgcn_rcpf(a)

__launch_bounds__(64)
__global__ void stn_kernel(const float* __restrict__ x,
                           const float* __restrict__ W1,
                           const float* __restrict__ W2,
                           const float* __restrict__ b2,
                           const float* __restrict__ W3,
                           const float* __restrict__ W4,
                           float* __restrict__ out,
                           const int S, const int B) {
    const int b = blockIdx.x * 64 + threadIdx.x;
    const float K = 2.88539008177792681472f;  // 2/ln(2): exp(2y) = exp2(K*y)

    // ---- fold weights (uniform across threads, once per 4096-step loop) ----
    float kw1x[4], kw1s[4];
#pragma unroll
    for (int i = 0; i < 4; ++i) {
        kw1x[i] = K * W1[2 * i + 0];
        kw1s[i] = K * W1[2 * i + 1];
    }
    float A2[4], B2m[16], A3[4], B3m[16];
#pragma unroll
    for (int i = 0; i < 4; ++i) {
        float r2 = 0.f, r3 = 0.f;
#pragma unroll
        for (int j = 0; j < 4; ++j) {
            r2 += W2[4 * i + j];
            r3 += W3[4 * i + j];
            B2m[4 * i + j] = -2.f * K * W2[4 * i + j];
            B3m[4 * i + j] = -2.f * K * W3[4 * i + j];
        }
        A2[i] = K * (b2[i] + r2);
        A3[i] = K * r3;
    }
    float A4 = 0.f, B4[4];
#pragma unroll
    for (int j = 0; j < 4; ++j) {
        A4 += W4[j];
        B4[j] = -2.f * W4[j];
    }

    // ---- sequential scan, unrolled x8 with one-block-ahead x prefetch ----
    float s = 0.f;
    constexpr int U = 8;
    const float* xp = x + b;
    float* op = out + b;

    float xb[U];
#pragma unroll
    for (int u = 0; u < U; ++u) xb[u] = xp[u * B];
    xp += (size_t)U * B;

    for (int t0 = 0; t0 < S; t0 += U) {
        float xn[U];
        const bool more = (t0 + U) < S;
        if (more) {
#pragma unroll
            for (int u = 0; u < U; ++u) xn[u] = xp[u * B];
            xp += (size_t)U * B;
        }
#pragma unroll
        for (int u = 0; u < U; ++u) {
            const float xv = xb[u];
            float z1[4], z2[4], z3[4];
#pragma unroll
            for (int i = 0; i < 4; ++i) {
                float a = fmaf(kw1s[i], s, kw1x[i] * xv);
                z1[i] = RCPF(1.f + EXP2F(a));
            }
#pragma unroll
            for (int i = 0; i < 4; ++i) {
                float a = A2[i];
#pragma unroll
                for (int j = 0; j < 4; ++j) a = fmaf(B2m[4 * i + j], z1[j], a);
                z2[i] = RCPF(1.f + EXP2F(a));
            }
#pragma unroll
            for (int i = 0; i < 4; ++i) {
                float a = A3[i];
#pragma unroll
                for (int j = 0; j < 4; ++j) a = fmaf(B3m[4 * i + j], z2[j], a);
                z3[i] = RCPF(1.f + EXP2F(a));
            }
            float d = A4;
#pragma unroll
            for (int j = 0; j < 4; ++j) d = fmaf(B4[j], z3[j], d);
            s = fmaf(2.f, d, s);
            op[(size_t)(t0 + u) * B] = s;
        }
        if (more) {
#pragma unroll
            for (int u = 0; u < U; ++u) xb[u] = xn[u];
        }
    }
}

extern "C" void kernel_launch(void* const* d_in, const int* in_sizes, int n_in,
                              void* d_out, int out_size, void* d_ws, size_t ws_size,
                              hipStream_t stream) {
    const float* x  = (const float*)d_in[0];
    const float* W1 = (const float*)d_in[1];
    const float* W2 = (const float*)d_in[2];
    const float* b2 = (const float*)d_in[3];
    const float* W3 = (const float*)d_in[4];
    const float* W4 = (const float*)d_in[5];
    float* out = (float*)d_out;

    const int B = 16384;
    const int S = out_size / B;  // 4096

    stn_kernel<<<B / 64, 64, 0, stream>>>(x, W1, W2, b2, W3, W4, out, S, B);
}